// Round 1
// baseline (221.103 us; speedup 1.0000x reference)
//
#include <hip/hip_runtime.h>

// PQN soft-quantization: x[32768,1024], c[1024,256] -> out[32768,1024] (f32)
// D=1024, M=8 subspaces of L=128, K=256 codes, scale 2*ALPHA=20.
//
// Fused per-wave pipeline, one block per CU, codebook subspace staged in LDS
// (f16, both layouts), softmax fully in registers, f16 MFMA 16x16x32.

#define D_  1024
#define M_  8
#define K_  256
#define L_  128
#define BZ_ 32768

typedef _Float16 f16;
typedef f16 f16x8 __attribute__((ext_vector_type(8)));
typedef f16 f16x4 __attribute__((ext_vector_type(4)));
typedef f16 f16x2 __attribute__((ext_vector_type(2)));
typedef float f32x4 __attribute__((ext_vector_type(4)));

// LDS leading dims (f16 elements). Row strides are 16 mod 128 bytes so the
// 16-lane ds_read_b128 fragment reads rotate start banks by 4 (minimal 2-way).
#define CSA_LD 136   // csA[256][136] : [code][l]   (transposed, phase-1 A)
#define CSB_LD 264   // csB[128][264] : [l][code]   (row-major,  phase-2 A)

__global__ __launch_bounds__(256, 1)
void pqn_kernel(const float* __restrict__ x, const float* __restrict__ c,
                float* __restrict__ out) {
    __shared__ f16 csA[256 * CSA_LD];   // 69,632 B
    __shared__ f16 csB[128 * CSB_LD];   // 67,584 B  (total 137,216 B)

    const int tid  = threadIdx.x;
    const int m    = blockIdx.x >> 5;   // 32 blocks per subspace
    const int bm   = blockIdx.x & 31;
    const int lane = tid & 63;
    const int w    = tid >> 6;          // wave in block (0..3)
    const int n    = lane & 15;
    const int g    = lane >> 4;         // quarter-wave (0..3)
    const int wi   = bm * 4 + w;        // wave index within subspace (0..127)

    // ---- stage codebook subspace m into LDS in both layouts (f16) ----
    const float* cm = c + (size_t)m * L_ * K_;   // cm[l*256 + k]
    #pragma unroll
    for (int itg = 0; itg < 16; ++itg) {
        int idx = itg * 256 + tid;
        int l   = (idx >> 6) * 2;        // even row 0..126
        int c4  = (idx & 63) << 2;       // code 0..252 step 4
        float4 a = *reinterpret_cast<const float4*>(cm + (size_t)l * K_ + c4);
        float4 b = *reinterpret_cast<const float4*>(cm + (size_t)(l + 1) * K_ + c4);
        f16x4 va = { (f16)a.x, (f16)a.y, (f16)a.z, (f16)a.w };
        f16x4 vb = { (f16)b.x, (f16)b.y, (f16)b.z, (f16)b.w };
        *reinterpret_cast<f16x4*>(&csB[l * CSB_LD + c4])       = va;
        *reinterpret_cast<f16x4*>(&csB[(l + 1) * CSB_LD + c4]) = vb;
        #pragma unroll
        for (int j = 0; j < 4; ++j) {
            f16x2 t = { va[j], vb[j] };
            *reinterpret_cast<f16x2*>(&csA[(c4 + j) * CSA_LD + l]) = t;
        }
    }
    __syncthreads();

    const int csa_base = n * CSA_LD + g * 8;
    const int csb_base = n * CSB_LD + g * 8;

    // prefetch first row-tile: lane holds 32 floats of row (tile*16 + n)
    float4 xa[8];
    {
        const float* px = x + (size_t)(wi * 16 + n) * D_ + m * L_ + g * 8;
        #pragma unroll
        for (int ks = 0; ks < 4; ++ks) {
            xa[2 * ks]     = *reinterpret_cast<const float4*>(px + ks * 32);
            xa[2 * ks + 1] = *reinterpret_cast<const float4*>(px + ks * 32 + 4);
        }
    }

    for (int it = 0; it < 16; ++it) {
        const int r0 = (it * 128 + wi) * 16;

        // ---- row L2 norm (f32, exact) -> logit scale 20/||x|| ----
        float ss = 0.f;
        #pragma unroll
        for (int j = 0; j < 8; ++j) {
            float4 a = xa[j];
            ss = fmaf(a.x, a.x, ss); ss = fmaf(a.y, a.y, ss);
            ss = fmaf(a.z, a.z, ss); ss = fmaf(a.w, a.w, ss);
        }
        ss += __shfl_xor(ss, 16);
        ss += __shfl_xor(ss, 32);
        const float fac = 20.0f / fmaxf(sqrtf(ss), 1e-12f);

        // ---- B1 fragments: raw x as f16 (k = l-dim, col = sample row) ----
        f16x8 bf[4];
        #pragma unroll
        for (int ks = 0; ks < 4; ++ks) {
            float4 lo = xa[2 * ks], hi = xa[2 * ks + 1];
            bf[ks][0] = (f16)lo.x; bf[ks][1] = (f16)lo.y;
            bf[ks][2] = (f16)lo.z; bf[ks][3] = (f16)lo.w;
            bf[ks][4] = (f16)hi.x; bf[ks][5] = (f16)hi.y;
            bf[ks][6] = (f16)hi.z; bf[ks][7] = (f16)hi.w;
        }

        // ---- prefetch next row-tile (hidden under phases below) ----
        if (it < 15) {
            const float* px = x + (size_t)(((it + 1) * 128 + wi) * 16 + n) * D_
                                + m * L_ + g * 8;
            #pragma unroll
            for (int ks = 0; ks < 4; ++ks) {
                xa[2 * ks]     = *reinterpret_cast<const float4*>(px + ks * 32);
                xa[2 * ks + 1] = *reinterpret_cast<const float4*>(px + ks * 32 + 4);
            }
        }

        // ---- phase 1: z^T[code][brow] = cs^T · x^T ----
        f32x4 acc[16];
        const f32x4 fzero = {0.f, 0.f, 0.f, 0.f};
        #pragma unroll
        for (int t = 0; t < 16; ++t) acc[t] = fzero;
        #pragma unroll
        for (int ks = 0; ks < 4; ++ks) {
            #pragma unroll
            for (int t = 0; t < 16; ++t) {
                f16x8 af = *reinterpret_cast<const f16x8*>(
                    &csA[csa_base + t * 16 * CSA_LD + ks * 32]);
                acc[t] = __builtin_amdgcn_mfma_f32_16x16x32_f16(af, bf[ks], acc[t], 0, 0, 0);
            }
        }

        // ---- scale + in-register softmax over 256 codes ----
        // lane holds codes {t*16 + g*4 + r}; xor16/32 reduce across g.
        float zmax = -3.0e38f;
        #pragma unroll
        for (int t = 0; t < 16; ++t) {
            #pragma unroll
            for (int r = 0; r < 4; ++r) {
                acc[t][r] *= fac;
                zmax = fmaxf(zmax, acc[t][r]);
            }
        }
        zmax = fmaxf(zmax, __shfl_xor(zmax, 16));
        zmax = fmaxf(zmax, __shfl_xor(zmax, 32));
        float S = 0.f;
        #pragma unroll
        for (int t = 0; t < 16; ++t) {
            #pragma unroll
            for (int r = 0; r < 4; ++r) {
                float p = __expf(acc[t][r] - zmax);
                acc[t][r] = p;          // unnormalized; 1/S applied at store
                S += p;
            }
        }
        S += __shfl_xor(S, 16);
        S += __shfl_xor(S, 32);
        const float invS = 1.0f / S;

        // ---- phase 2: out^T[l][brow] = cs · w^T ----
        f32x4 acc2[8];
        #pragma unroll
        for (int t = 0; t < 8; ++t) acc2[t] = fzero;
        #pragma unroll
        for (int ks2 = 0; ks2 < 8; ++ks2) {
            // build B2 fragment: lane needs p(code = ks2*32 + g*8 + i, brow n).
            // source: tile 2*ks2 + (g>>1), reg i&3, lane (2*(g&1)+(i>>2))*16 + n
            f16x8 pb;
            #pragma unroll
            for (int i = 0; i < 8; ++i) {
                const int src = (2 * (g & 1) + (i >> 2)) * 16 + n;
                float v0 = __shfl(acc[2 * ks2][i & 3], src);
                float v1 = __shfl(acc[2 * ks2 + 1][i & 3], src);
                pb[i] = (f16)((g < 2) ? v0 : v1);
            }
            #pragma unroll
            for (int nt = 0; nt < 8; ++nt) {
                f16x8 a2 = *reinterpret_cast<const f16x8*>(
                    &csB[csb_base + nt * 16 * CSB_LD + ks2 * 32]);
                acc2[nt] = __builtin_amdgcn_mfma_f32_16x16x32_f16(a2, pb, acc2[nt], 0, 0, 0);
            }
        }

        // ---- store: lane writes 4 consecutive cols per l-tile (16B) ----
        float* po = out + (size_t)(r0 + n) * D_ + m * L_;
        #pragma unroll
        for (int nt = 0; nt < 8; ++nt) {
            f32x4 v;
            #pragma unroll
            for (int r = 0; r < 4; ++r) v[r] = acc2[nt][r] * invS;
            *reinterpret_cast<f32x4*>(po + nt * 16 + g * 4) = v;
        }
    }
}

extern "C" void kernel_launch(void* const* d_in, const int* in_sizes, int n_in,
                              void* d_out, int out_size, void* d_ws, size_t ws_size,
                              hipStream_t stream) {
    const float* x = (const float*)d_in[0];   // [32768, 1024] f32
    const float* c = (const float*)d_in[1];   // [1024, 256]   f32
    float* out = (float*)d_out;               // [32768, 1024] f32
    (void)in_sizes; (void)n_in; (void)out_size; (void)d_ws; (void)ws_size;

    pqn_kernel<<<dim3(256), dim3(256), 0, stream>>>(x, c, out);
}